// Round 1
// baseline (2544.301 us; speedup 1.0000x reference)
//
#include <hip/hip_runtime.h>
#include <math.h>

static constexpr int HEADS  = 8;
static constexpr int DHEAD  = 96;
static constexpr int INNER  = 768;   // 8*96
static constexpr int NPEP   = 128;
static constexpr int MPRO   = 2048;
static constexpr int NBATCH = 16;
static constexpr float ATT_SCALE = 0.10206207261596577f;  // 96^-0.5
static constexpr float NEGF   = -1000000.0f;
static constexpr float LN_EPS = 1e-5f;

// ---------------------------------------------------------------------------
// Generic fp32 tiled GEMM.
//  TA=false: A is MxK (lda = row stride). TA=true: A is KxM.
//  TB=false: B is KxN.                    TB=true: B is NxK.
//  Batched over blockIdx.z = b*HEADS + h with separate (b,h) strides so we can
//  slice per-head columns out of (rows, 768) tensors.
//  EPI==1: scores epilogue: v = v*SCALE, masked to NEG by row/col masks.
// Assumes: K % BK == 0, all leading dims % 4 == 0, M % 4 == 0, N % 4 == 0.
// ---------------------------------------------------------------------------
template<int BM, int BN, int BK, int TM, int TN, bool TA, bool TB, int EPI>
__global__ __launch_bounds__(256) void gemm_f32(
    const float* __restrict__ A, const float* __restrict__ B,
    float* __restrict__ C,
    int M, int N, int K, int lda, int ldb, int ldc,
    long sAb, long sAh, long sBb, long sBh, long sCb, long sCh,
    const int* __restrict__ maskRow, const int* __restrict__ maskCol)
{
    __shared__ float As[BK][BM + 4];
    __shared__ float Bs[BK][BN + 4];

    const int tid = threadIdx.x;            // 256 threads
    const int tx  = tid % (BN / TN);        // 0..15
    const int ty  = tid / (BN / TN);        // 0..15
    const int n0  = blockIdx.x * BN;
    const int m0  = blockIdx.y * BM;
    const int z   = blockIdx.z;
    const int zb  = z / HEADS;
    const int zh  = z - zb * HEADS;

    const float* Ab = A + zb * sAb + zh * sAh;
    const float* Bb = B + zb * sBb + zh * sBh;
    float*       Cb = C + zb * sCb + zh * sCh;

    float acc[TM][TN];
#pragma unroll
    for (int i = 0; i < TM; ++i)
#pragma unroll
        for (int j = 0; j < TN; ++j) acc[i][j] = 0.f;

    for (int k0 = 0; k0 < K; k0 += BK) {
        // ---- load A tile into As[k][m] ----
        if (!TA) {
            constexpr int V = BM * (BK / 4);
            for (int i = tid; i < V; i += 256) {
                const int r = i / (BK / 4);
                const int q = i % (BK / 4);
                const int gm = m0 + r, gk = k0 + q * 4;
                float4 v = make_float4(0.f, 0.f, 0.f, 0.f);
                if (gm < M)
                    v = *reinterpret_cast<const float4*>(Ab + (long)gm * lda + gk);
                As[q * 4 + 0][r] = v.x;
                As[q * 4 + 1][r] = v.y;
                As[q * 4 + 2][r] = v.z;
                As[q * 4 + 3][r] = v.w;
            }
        } else {
            constexpr int V = BK * (BM / 4);
            for (int i = tid; i < V; i += 256) {
                const int r = i / (BM / 4);
                const int c = i % (BM / 4);
                const int gk = k0 + r, gm = m0 + c * 4;
                float4 v = make_float4(0.f, 0.f, 0.f, 0.f);
                if (gm < M)
                    v = *reinterpret_cast<const float4*>(Ab + (long)gk * lda + gm);
                As[r][c * 4 + 0] = v.x;
                As[r][c * 4 + 1] = v.y;
                As[r][c * 4 + 2] = v.z;
                As[r][c * 4 + 3] = v.w;
            }
        }
        // ---- load B tile into Bs[k][n] ----
        if (!TB) {
            constexpr int V = BK * (BN / 4);
            for (int i = tid; i < V; i += 256) {
                const int r = i / (BN / 4);
                const int c = i % (BN / 4);
                const int gk = k0 + r, gn = n0 + c * 4;
                float4 v = make_float4(0.f, 0.f, 0.f, 0.f);
                if (gn < N)
                    v = *reinterpret_cast<const float4*>(Bb + (long)gk * ldb + gn);
                Bs[r][c * 4 + 0] = v.x;
                Bs[r][c * 4 + 1] = v.y;
                Bs[r][c * 4 + 2] = v.z;
                Bs[r][c * 4 + 3] = v.w;
            }
        } else {
            constexpr int V = BN * (BK / 4);
            for (int i = tid; i < V; i += 256) {
                const int r = i / (BK / 4);
                const int q = i % (BK / 4);
                const int gn = n0 + r, gk = k0 + q * 4;
                float4 v = make_float4(0.f, 0.f, 0.f, 0.f);
                if (gn < N)
                    v = *reinterpret_cast<const float4*>(Bb + (long)gn * ldb + gk);
                Bs[q * 4 + 0][r] = v.x;
                Bs[q * 4 + 1][r] = v.y;
                Bs[q * 4 + 2][r] = v.z;
                Bs[q * 4 + 3][r] = v.w;
            }
        }
        __syncthreads();

#pragma unroll
        for (int kk = 0; kk < BK; ++kk) {
            float a[TM], bv[TN];
#pragma unroll
            for (int i = 0; i < TM; ++i) a[i] = As[kk][ty * TM + i];
#pragma unroll
            for (int j = 0; j < TN; ++j) bv[j] = Bs[kk][tx * TN + j];
#pragma unroll
            for (int i = 0; i < TM; ++i)
#pragma unroll
                for (int j = 0; j < TN; ++j)
                    acc[i][j] = fmaf(a[i], bv[j], acc[i][j]);
        }
        __syncthreads();
    }

    // ---- store (+ optional scores epilogue) ----
#pragma unroll
    for (int i = 0; i < TM; ++i) {
        const int gm = m0 + ty * TM + i;
        if (gm >= M) continue;
#pragma unroll
        for (int j = 0; j < TN; ++j) {
            const int gn = n0 + tx * TN + j;
            if (gn >= N) continue;
            float v = acc[i][j];
            if (EPI == 1) {
                v *= ATT_SCALE;
                if (maskRow[zb * NPEP + gm] == 0 || maskCol[zb * MPRO + gn] == 0)
                    v = NEGF;
            }
            Cb[(long)gm * ldc + gn] = v;
        }
    }
}

// ---------------------------------------------------------------------------
// Row softmax over 2048 columns, in place. One block per row.
// ---------------------------------------------------------------------------
__global__ __launch_bounds__(256) void softmax_kernel(float* __restrict__ attn)
{
    __shared__ float red[256];
    const long row = blockIdx.x;
    float* p = attn + row * (long)MPRO;
    const int tid = threadIdx.x;

    float v[8];
    float mx = -3.4e38f;
#pragma unroll
    for (int k = 0; k < 8; ++k) {
        v[k] = p[tid + k * 256];
        mx = fmaxf(mx, v[k]);
    }
    red[tid] = mx;
    __syncthreads();
    for (int s = 128; s > 0; s >>= 1) {
        if (tid < s) red[tid] = fmaxf(red[tid], red[tid + s]);
        __syncthreads();
    }
    mx = red[0];
    __syncthreads();

    float sum = 0.f;
#pragma unroll
    for (int k = 0; k < 8; ++k) {
        v[k] = expf(v[k] - mx);
        sum += v[k];
    }
    red[tid] = sum;
    __syncthreads();
    for (int s = 128; s > 0; s >>= 1) {
        if (tid < s) red[tid] += red[tid + s];
        __syncthreads();
    }
    const float inv = 1.0f / red[0];
#pragma unroll
    for (int k = 0; k < 8; ++k) p[tid + k * 256] = v[k] * inv;
}

// ---------------------------------------------------------------------------
// out = LayerNorm(tmp + bias + res) * g + b. One block per 768-wide row.
// ---------------------------------------------------------------------------
__global__ __launch_bounds__(256) void bias_res_ln(
    const float* __restrict__ tmp, const float* __restrict__ bias,
    const float* __restrict__ res, const float* __restrict__ gam,
    const float* __restrict__ bet, float* __restrict__ out)
{
    __shared__ float red[256];
    const long row = blockIdx.x;
    const float* t = tmp + row * INNER;
    const float* r = res + row * INNER;
    float* o = out + row * INNER;
    const int tid = threadIdx.x;

    float v[3];
    float s = 0.f;
#pragma unroll
    for (int k = 0; k < 3; ++k) {
        const int c = tid + k * 256;
        v[k] = t[c] + bias[c] + r[c];
        s += v[k];
    }
    red[tid] = s;
    __syncthreads();
    for (int st = 128; st > 0; st >>= 1) {
        if (tid < st) red[tid] += red[tid + st];
        __syncthreads();
    }
    const float mu = red[0] * (1.0f / INNER);
    __syncthreads();

    float vs = 0.f;
#pragma unroll
    for (int k = 0; k < 3; ++k) {
        const float d = v[k] - mu;
        vs += d * d;
    }
    red[tid] = vs;
    __syncthreads();
    for (int st = 128; st > 0; st >>= 1) {
        if (tid < st) red[tid] += red[tid + st];
        __syncthreads();
    }
    const float rstd = rsqrtf(red[0] * (1.0f / INNER) + LN_EPS);
#pragma unroll
    for (int k = 0; k < 3; ++k) {
        const int c = tid + k * 256;
        o[c] = (v[k] - mu) * rstd * gam[c] + bet[c];
    }
}

// ---------------------------------------------------------------------------
extern "C" void kernel_launch(void* const* d_in, const int* in_sizes, int n_in,
                              void* d_out, int out_size, void* d_ws, size_t ws_size,
                              hipStream_t stream)
{
    (void)in_sizes; (void)n_in; (void)out_size; (void)ws_size;

    const float* peptide = (const float*)d_in[0];   // (16,128,768)
    const float* protein = (const float*)d_in[1];   // (16,2048,768)
    const int*   pepm    = (const int*)  d_in[2];   // (16,128)
    const int*   prom    = (const int*)  d_in[3];   // (16,2048)
    const float* Wq      = (const float*)d_in[4];
    const float* Wk      = (const float*)d_in[5];
    const float* Wv_prot = (const float*)d_in[6];
    const float* Wv_pep  = (const float*)d_in[7];
    const float* Wo_prot = (const float*)d_in[8];
    const float* bo_prot = (const float*)d_in[9];
    const float* Wo_pep  = (const float*)d_in[10];
    const float* bo_pep  = (const float*)d_in[11];
    const float* ln_g    = (const float*)d_in[12];
    const float* ln_b    = (const float*)d_in[13];

    // workspace layout (floats); careful aliasing keeps it at ~204 MiB
    float* ws   = (float*)d_ws;
    float* bufK  = ws;                    // k:      16*2048*768 = 25165824
    float* bufV  = ws + 25165824;         // v_prot: 25165824
    float* bufQ  = ws + 50331648;         // q:      1572864
    float* bufVp = ws + 51904512;         // v_pep:  1572864
    float* bufOP = bufQ;                  // out_prot_pre (q dead after scores)
    float* bufPP = bufK;                  // out_pep_pre  (k dead after scores)
    float* bufT  = bufV;                  // GEMM tmp     (v_prot dead after step 7)

    float* outP = (float*)d_out;                 // (16,128,768)
    float* outQ = outP + 16 * 128 * 768;         // (16,2048,768)
    float* attn = outQ + 16 * 2048 * 768;        // (16,8,128,2048)

    const dim3 blk(256);
    const long sAttnB = (long)HEADS * NPEP * MPRO;
    const long sAttnH = (long)NPEP * MPRO;

    // 1. q = peptide @ Wq   (2048 x 768 x 768)
    gemm_f32<64,64,16,4,4,false,false,0><<<dim3(12,32,1),blk,0,stream>>>(
        peptide, Wq, bufQ, NBATCH*NPEP, INNER, INNER, INNER, INNER, INNER,
        0,0,0,0,0,0,nullptr,nullptr);
    // 2. k = protein @ Wk   (32768 x 768 x 768)
    gemm_f32<128,128,16,8,8,false,false,0><<<dim3(6,256,1),blk,0,stream>>>(
        protein, Wk, bufK, NBATCH*MPRO, INNER, INNER, INNER, INNER, INNER,
        0,0,0,0,0,0,nullptr,nullptr);
    // 3. v_prot = protein @ Wv_prot
    gemm_f32<128,128,16,8,8,false,false,0><<<dim3(6,256,1),blk,0,stream>>>(
        protein, Wv_prot, bufV, NBATCH*MPRO, INNER, INNER, INNER, INNER, INNER,
        0,0,0,0,0,0,nullptr,nullptr);
    // 4. v_pep = peptide @ Wv_pep
    gemm_f32<64,64,16,4,4,false,false,0><<<dim3(12,32,1),blk,0,stream>>>(
        peptide, Wv_pep, bufVp, NBATCH*NPEP, INNER, INNER, INNER, INNER, INNER,
        0,0,0,0,0,0,nullptr,nullptr);
    // 5. scores: attn[b,h,n,m] = scale * q . k  (masked)   NT, batched over b*h
    gemm_f32<64,64,16,4,4,false,true,1><<<dim3(32,2,128),blk,0,stream>>>(
        bufQ, bufK, attn, NPEP, MPRO, DHEAD, INNER, INNER, MPRO,
        (long)NPEP*INNER, (long)DHEAD, (long)MPRO*INNER, (long)DHEAD,
        sAttnB, sAttnH, pepm, prom);
    // 6. softmax rows (in place, 16*8*128 rows)
    softmax_kernel<<<dim3(16384),blk,0,stream>>>(attn);
    // 7. out_prot_pre[b,n,h,d] = attn @ v_prot   NN, batched
    gemm_f32<64,64,16,4,4,false,false,0><<<dim3(2,2,128),blk,0,stream>>>(
        attn, bufV, bufOP, NPEP, DHEAD, MPRO, MPRO, INNER, INNER,
        sAttnB, sAttnH, (long)MPRO*INNER, (long)DHEAD,
        (long)NPEP*INNER, (long)DHEAD, nullptr,nullptr);
    // 8. tmp_prot = out_prot_pre @ Wo_prot  (2048 x 768 x 768)
    gemm_f32<64,64,16,4,4,false,false,0><<<dim3(12,32,1),blk,0,stream>>>(
        bufOP, Wo_prot, bufT, NBATCH*NPEP, INNER, INNER, INNER, INNER, INNER,
        0,0,0,0,0,0,nullptr,nullptr);
    // 9. out_protein = LN(tmp_prot + bo_prot + peptide)
    bias_res_ln<<<dim3(NBATCH*NPEP),blk,0,stream>>>(
        bufT, bo_prot, peptide, ln_g, ln_b, outP);
    // 10. out_pep_pre[b,m,h,d] = attn^T @ v_pep  TN, batched
    gemm_f32<64,64,16,4,4,true,false,0><<<dim3(2,32,128),blk,0,stream>>>(
        attn, bufVp, bufPP, MPRO, DHEAD, NPEP, MPRO, INNER, INNER,
        sAttnB, sAttnH, (long)NPEP*INNER, (long)DHEAD,
        (long)MPRO*INNER, (long)DHEAD, nullptr,nullptr);
    // 11. tmp_pep = out_pep_pre @ Wo_pep  (32768 x 768 x 768)
    gemm_f32<128,128,16,8,8,false,false,0><<<dim3(6,256,1),blk,0,stream>>>(
        bufPP, Wo_pep, bufT, NBATCH*MPRO, INNER, INNER, INNER, INNER, INNER,
        0,0,0,0,0,0,nullptr,nullptr);
    // 12. out_peptide = LN(tmp_pep + bo_pep + protein)
    bias_res_ln<<<dim3(NBATCH*MPRO),blk,0,stream>>>(
        bufT, bo_pep, protein, ln_g, ln_b, outQ);
}

// Round 2
// 913.676 us; speedup vs baseline: 2.7847x; 2.7847x over previous
//
#include <hip/hip_runtime.h>
#include <math.h>

static constexpr int HEADS  = 8;
static constexpr int DHEAD  = 96;
static constexpr int INNER  = 768;
static constexpr int NPEP   = 128;
static constexpr int MPRO   = 2048;
static constexpr int NBATCH = 16;
static constexpr float ATT_SCALE = 0.10206207261596577f;  // 96^-0.5
static constexpr float NEGF   = -1000000.0f;
static constexpr float LN_EPS = 1e-5f;

typedef __attribute__((ext_vector_type(8))) short bf16x8;
typedef __attribute__((ext_vector_type(4))) float f32x4;

__device__ __forceinline__ unsigned short f2b(float f) {
    unsigned u = __builtin_bit_cast(unsigned, f);
    u += 0x7fffu + ((u >> 16) & 1u);          // RNE
    return (unsigned short)(u >> 16);
}

__device__ __forceinline__ void async16(const unsigned short* g, unsigned short* l) {
    __builtin_amdgcn_global_load_lds(
        (const __attribute__((address_space(1))) void*)g,
        (__attribute__((address_space(3))) void*)l, 16, 0, 0);
}

// ---------------------------------------------------------------------------
// m97-style bf16 MFMA GEMM, B^T operand form:
//   C[row, col] = sum_k A[row, k] * B[col, k]
// A: M x K row-major bf16 (lda).  B: N x K row-major bf16 (ldb).
// 128x128 tile, BK=32, 256 threads = 4 waves (2x2 of 64x64).
// Batched over blockIdx.z = b*HEADS+h via (b,h) strides.
// MODE 0: C fp32 row-major (ldc), batched.
// MODE 1: C fp32 scores: *SCALE, masked by mRow/mCol, batched.
// MODE 2: C bf16 row-major (ldc), batched. (col < N guard)
// MODE 3: C bf16 head-split   (b,h,r,d): gm->(b,r via lenShift), gn->(h,d).
// MODE 4: C bf16 head-split-T (b,h,d,r).
// Requires: M % 128 == 0, K % 32 == 0, 16B-aligned rows (lda,ldb even*8).
// ---------------------------------------------------------------------------
template<int MODE>
__global__ __launch_bounds__(256) void gemm_bf16(
    const unsigned short* __restrict__ A, const unsigned short* __restrict__ B,
    void* __restrict__ C,
    int M, int N, int K, int lda, int ldb, int ldc,
    long sAb, long sAh, long sBb, long sBh, long sCb, long sCh,
    const int* __restrict__ mRow, const int* __restrict__ mCol, int lenShift)
{
    __shared__ unsigned short As[128 * 32];
    __shared__ unsigned short Bs[128 * 32];

    const int tid = threadIdx.x;
    const int n0  = blockIdx.x * 128;
    const int m0  = blockIdx.y * 128;
    const int z   = blockIdx.z;
    const int zb  = z >> 3, zh = z & 7;

    const unsigned short* Ab = A + zb * sAb + zh * sAh;
    const unsigned short* Bb = B + zb * sBb + zh * sBh;

    // staging map: chunk c = issue*256+tid -> tile row c>>2, k-subcol (c&3)*8
    const int rS = tid >> 2;
    const int kS = (tid & 3) * 8;
    const int wave = tid >> 6;
    unsigned short* ldsA0 = As + wave * 512;            // + lane*8 implicit
    unsigned short* ldsA1 = As + 2048 + wave * 512;
    unsigned short* ldsB0 = Bs + wave * 512;
    unsigned short* ldsB1 = Bs + 2048 + wave * 512;

    const int lane = tid & 63;
    const int l16  = lane & 15;
    const int quad = lane >> 4;
    const int wr   = (wave >> 1) * 64;
    const int wc   = (wave & 1) * 64;

    f32x4 acc[4][4];
#pragma unroll
    for (int i = 0; i < 4; ++i)
#pragma unroll
        for (int j = 0; j < 4; ++j) acc[i][j] = (f32x4){0.f, 0.f, 0.f, 0.f};

    for (int k0 = 0; k0 < K; k0 += 32) {
        async16(Ab + (long)(m0 + rS) * lda + k0 + kS, ldsA0);
        async16(Ab + (long)(m0 + 64 + rS) * lda + k0 + kS, ldsA1);
        int bR0 = n0 + rS;      if (bR0 > N - 1) bR0 = N - 1;   // N=96 guard
        int bR1 = n0 + 64 + rS; if (bR1 > N - 1) bR1 = N - 1;
        async16(Bb + (long)bR0 * ldb + k0 + kS, ldsB0);
        async16(Bb + (long)bR1 * ldb + k0 + kS, ldsB1);
        __syncthreads();

        bf16x8 af[4], bfr[4];
#pragma unroll
        for (int i = 0; i < 4; ++i)
            af[i] = *reinterpret_cast<const bf16x8*>(&As[(wr + i * 16 + l16) * 32 + quad * 8]);
#pragma unroll
        for (int j = 0; j < 4; ++j)
            bfr[j] = *reinterpret_cast<const bf16x8*>(&Bs[(wc + j * 16 + l16) * 32 + quad * 8]);
#pragma unroll
        for (int i = 0; i < 4; ++i)
#pragma unroll
            for (int j = 0; j < 4; ++j)
                acc[i][j] = __builtin_amdgcn_mfma_f32_16x16x32_bf16(af[i], bfr[j], acc[i][j], 0, 0, 0);
        __syncthreads();
    }

    // epilogue: C/D layout col = lane&15, row = quad*4 + reg
#pragma unroll
    for (int i = 0; i < 4; ++i) {
#pragma unroll
        for (int j = 0; j < 4; ++j) {
            const int col = n0 + wc + j * 16 + l16;
            if ((MODE == 0 || MODE == 2) && col >= N) continue;
#pragma unroll
            for (int r = 0; r < 4; ++r) {
                const int row = m0 + wr + i * 16 + quad * 4 + r;
                float v = acc[i][j][r];
                if (MODE == 0) {
                    ((float*)C)[zb * sCb + zh * sCh + (long)row * ldc + col] = v;
                } else if (MODE == 1) {
                    v *= ATT_SCALE;
                    if (mRow[zb * NPEP + row] == 0 || mCol[zb * MPRO + col] == 0) v = NEGF;
                    ((float*)C)[zb * sCb + zh * sCh + (long)row * ldc + col] = v;
                } else if (MODE == 2) {
                    ((unsigned short*)C)[zb * sCb + zh * sCh + (long)row * ldc + col] = f2b(v);
                } else if (MODE == 3) {
                    const int b = row >> lenShift, rr = row & ((1 << lenShift) - 1);
                    const int h = col / 96, d = col % 96;
                    ((unsigned short*)C)[(((long)(b * 8 + h) << lenShift) + rr) * 96 + d] = f2b(v);
                } else { // MODE 4
                    const int b = row >> lenShift, rr = row & ((1 << lenShift) - 1);
                    const int h = col / 96, d = col % 96;
                    ((unsigned short*)C)[(((long)(b * 8 + h) * 96 + d) << lenShift) + rr] = f2b(v);
                }
            }
        }
    }
}

// ---------------------------------------------------------------------------
__global__ __launch_bounds__(256) void conv_bf16_kernel(
    const float* __restrict__ in, unsigned short* __restrict__ out, int n4)
{
    const int i = blockIdx.x * 256 + threadIdx.x;
    if (i >= n4) return;
    float4 v = reinterpret_cast<const float4*>(in)[i];
    ushort4 o;
    o.x = f2b(v.x); o.y = f2b(v.y); o.z = f2b(v.z); o.w = f2b(v.w);
    reinterpret_cast<ushort4*>(out)[i] = o;
}

// weights: fp32 K x N (768x768) -> bf16 N x K (transposed), 6 at once via z
__global__ __launch_bounds__(256) void wtrans_kernel(
    const float* w0, const float* w1, const float* w2,
    const float* w3, const float* w4, const float* w5,
    unsigned short* o0, unsigned short* o1, unsigned short* o2,
    unsigned short* o3, unsigned short* o4, unsigned short* o5)
{
    const float* in; unsigned short* out;
    switch (blockIdx.z) {
        case 0: in = w0; out = o0; break;
        case 1: in = w1; out = o1; break;
        case 2: in = w2; out = o2; break;
        case 3: in = w3; out = o3; break;
        case 4: in = w4; out = o4; break;
        default: in = w5; out = o5; break;
    }
    __shared__ unsigned short t[32][33];
    const int bx = blockIdx.x * 32, by = blockIdx.y * 32;
    const int x = threadIdx.x, y = threadIdx.y;
#pragma unroll
    for (int i = 0; i < 32; i += 8)
        t[y + i][x] = f2b(in[(long)(by + y + i) * 768 + bx + x]);
    __syncthreads();
#pragma unroll
    for (int i = 0; i < 32; i += 8)
        out[(long)(bx + y + i) * 768 + by + x] = t[x][y + i];
}

// attn fp32 (b,h,128,2048) -> attnT bf16 (b,h,2048,128)
__global__ __launch_bounds__(256) void attn_trans_kernel(
    const float* __restrict__ attn, unsigned short* __restrict__ attnT)
{
    __shared__ unsigned short t[32][33];
    const long bi = (long)blockIdx.z * NPEP * MPRO;
    const long bo = (long)blockIdx.z * MPRO * NPEP;
    const int m0 = blockIdx.x * 32, n0 = blockIdx.y * 32;
    const int x = threadIdx.x, y = threadIdx.y;
#pragma unroll
    for (int i = 0; i < 32; i += 8)
        t[y + i][x] = f2b(attn[bi + (long)(n0 + y + i) * MPRO + m0 + x]);
    __syncthreads();
#pragma unroll
    for (int i = 0; i < 32; i += 8)
        attnT[bo + (long)(m0 + y + i) * NPEP + n0 + x] = t[x][y + i];
}

// row softmax over 2048, in place; also writes bf16 copy
__global__ __launch_bounds__(256) void softmax_kernel(
    float* __restrict__ attn, unsigned short* __restrict__ attn16)
{
    __shared__ float red[256];
    const long row = blockIdx.x;
    float* p = attn + row * (long)MPRO;
    unsigned short* p16 = attn16 + row * (long)MPRO;
    const int tid = threadIdx.x;

    float v[8];
    float mx = -3.4e38f;
#pragma unroll
    for (int k = 0; k < 8; ++k) { v[k] = p[tid + k * 256]; mx = fmaxf(mx, v[k]); }
    red[tid] = mx; __syncthreads();
    for (int s = 128; s > 0; s >>= 1) { if (tid < s) red[tid] = fmaxf(red[tid], red[tid + s]); __syncthreads(); }
    mx = red[0]; __syncthreads();

    float sum = 0.f;
#pragma unroll
    for (int k = 0; k < 8; ++k) { v[k] = expf(v[k] - mx); sum += v[k]; }
    red[tid] = sum; __syncthreads();
    for (int s = 128; s > 0; s >>= 1) { if (tid < s) red[tid] += red[tid + s]; __syncthreads(); }
    const float inv = 1.0f / red[0];
#pragma unroll
    for (int k = 0; k < 8; ++k) {
        const float o = v[k] * inv;
        p[tid + k * 256] = o;
        p16[tid + k * 256] = f2b(o);
    }
}

// out = LN(tmp + bias + res) * g + b, rows of 768
__global__ __launch_bounds__(256) void bias_res_ln(
    const float* __restrict__ tmp, const float* __restrict__ bias,
    const float* __restrict__ res, const float* __restrict__ gam,
    const float* __restrict__ bet, float* __restrict__ out)
{
    __shared__ float red[256];
    const long row = blockIdx.x;
    const float* t = tmp + row * INNER;
    const float* r = res + row * INNER;
    float* o = out + row * INNER;
    const int tid = threadIdx.x;

    float v[3]; float s = 0.f;
#pragma unroll
    for (int k = 0; k < 3; ++k) { const int c = tid + k * 256; v[k] = t[c] + bias[c] + r[c]; s += v[k]; }
    red[tid] = s; __syncthreads();
    for (int st = 128; st > 0; st >>= 1) { if (tid < st) red[tid] += red[tid + st]; __syncthreads(); }
    const float mu = red[0] * (1.0f / INNER); __syncthreads();

    float vs = 0.f;
#pragma unroll
    for (int k = 0; k < 3; ++k) { const float d = v[k] - mu; vs += d * d; }
    red[tid] = vs; __syncthreads();
    for (int st = 128; st > 0; st >>= 1) { if (tid < st) red[tid] += red[tid + st]; __syncthreads(); }
    const float rstd = rsqrtf(red[0] * (1.0f / INNER) + LN_EPS);
#pragma unroll
    for (int k = 0; k < 3; ++k) { const int c = tid + k * 256; o[c] = (v[k] - mu) * rstd * gam[c] + bet[c]; }
}

// ---------------------------------------------------------------------------
extern "C" void kernel_launch(void* const* d_in, const int* in_sizes, int n_in,
                              void* d_out, int out_size, void* d_ws, size_t ws_size,
                              hipStream_t stream)
{
    (void)in_sizes; (void)n_in; (void)out_size; (void)ws_size;

    const float* peptide = (const float*)d_in[0];
    const float* protein = (const float*)d_in[1];
    const int*   pepm    = (const int*)  d_in[2];
    const int*   prom    = (const int*)  d_in[3];
    const float* Wq      = (const float*)d_in[4];
    const float* Wk      = (const float*)d_in[5];
    const float* Wv_prot = (const float*)d_in[6];
    const float* Wv_pep  = (const float*)d_in[7];
    const float* Wo_prot = (const float*)d_in[8];
    const float* bo_prot = (const float*)d_in[9];
    const float* Wo_pep  = (const float*)d_in[10];
    const float* bo_pep  = (const float*)d_in[11];
    const float* ln_g    = (const float*)d_in[12];
    const float* ln_b    = (const float*)d_in[13];

    // --- workspace layout (byte offsets; total 167,510,016 B, aliased) ---
    char* ws = (char*)d_ws;
    auto U = [&](size_t off) { return (unsigned short*)(ws + off); };
    unsigned short* pro16  = U(0);           // 50331648 B, dead after vpT
    unsigned short* pep16  = U(50331648);    //  3145728 B, dead after vpepT
    unsigned short* q16    = U(53477376);    //  3145728 B, dead after scores
    unsigned short* k16    = U(56623104);    // 50331648 B, dead after scores
    unsigned short* vpT    = U(106954752);   // 50331648 B, dead after PV1
    unsigned short* vpepT  = U(157286400);   //  3145728 B, dead after PV2
    unsigned short* WT0    = U(160432128);   // 6 x 1179648 B, live throughout
    unsigned short* WT1    = U(160432128 + 1179648);
    unsigned short* WT2    = U(160432128 + 2 * 1179648);
    unsigned short* WT3    = U(160432128 + 3 * 1179648);
    unsigned short* WT4    = U(160432128 + 4 * 1179648);
    unsigned short* WT5    = U(160432128 + 5 * 1179648);
    unsigned short* attn16 = U(0);           // 67108864 B (softmax..PV1), over dead pro/pep/q/k-head
    unsigned short* attnT  = U(0);           // reuses attn16 region (transpose..PV2)
    unsigned short* opp    = U(67108864);    //  3145728 B (PV1..O1)
    float*          tmp1   = (float*)(ws + 70254592);   // 6291456 B (O1..LN1)
    unsigned short* opep   = U(100663296);   // 50331648 B (PV2..O2), over dead vpT head
    float*          tmp2   = (float*)(ws + 0);          // 100663296 B (O2..LN2), over dead attnT

    float* outP = (float*)d_out;
    float* outQ = outP + 16 * 128 * 768;
    float* attn = outQ + (long)16 * 2048 * 768;

    // --- bf16 conversions ---
    conv_bf16_kernel<<<24576, 256, 0, stream>>>(protein, pro16, 6291456);
    conv_bf16_kernel<<<1536, 256, 0, stream>>>(peptide, pep16, 393216);
    wtrans_kernel<<<dim3(24, 24, 6), dim3(32, 8), 0, stream>>>(
        Wq, Wk, Wv_prot, Wv_pep, Wo_prot, Wo_pep, WT0, WT1, WT2, WT3, WT4, WT5);

    // --- projections (head-split outputs) ---
    gemm_bf16<3><<<dim3(6, 16, 1), 256, 0, stream>>>(
        pep16, WT0, q16, 2048, 768, 768, 768, 768, 0,
        0, 0, 0, 0, 0, 0, nullptr, nullptr, 7);
    gemm_bf16<3><<<dim3(6, 256, 1), 256, 0, stream>>>(
        pro16, WT1, k16, 32768, 768, 768, 768, 768, 0,
        0, 0, 0, 0, 0, 0, nullptr, nullptr, 11);
    gemm_bf16<4><<<dim3(6, 256, 1), 256, 0, stream>>>(
        pro16, WT2, vpT, 32768, 768, 768, 768, 768, 0,
        0, 0, 0, 0, 0, 0, nullptr, nullptr, 11);
    gemm_bf16<4><<<dim3(6, 16, 1), 256, 0, stream>>>(
        pep16, WT3, vpepT, 2048, 768, 768, 768, 768, 0,
        0, 0, 0, 0, 0, 0, nullptr, nullptr, 7);

    // --- scores = scale * q . k, masked ---
    gemm_bf16<1><<<dim3(16, 1, 128), 256, 0, stream>>>(
        q16, k16, attn, 128, 2048, 96, 96, 96, 2048,
        98304L, 12288L, 1572864L, 196608L, 2097152L, 262144L, pepm, prom, 0);

    // --- softmax (fp32 in place + bf16 copy) ---
    softmax_kernel<<<16384, 256, 0, stream>>>(attn, attn16);

    // --- out_prot_pre = attn @ v_prot  -> bf16 (b, n, h*96+d) ---
    gemm_bf16<2><<<dim3(1, 1, 128), 256, 0, stream>>>(
        attn16, vpT, opp, 128, 96, 2048, 2048, 2048, 768,
        2097152L, 262144L, 1572864L, 196608L, 98304L, 96L, nullptr, nullptr, 0);

    // --- tmp1 = out_prot_pre @ Wo_prot ---
    gemm_bf16<0><<<dim3(6, 16, 1), 256, 0, stream>>>(
        opp, WT4, tmp1, 2048, 768, 768, 768, 768, 768,
        0, 0, 0, 0, 0, 0, nullptr, nullptr, 0);
    bias_res_ln<<<2048, 256, 0, stream>>>(tmp1, bo_prot, peptide, ln_g, ln_b, outP);

    // --- attn^T bf16 ---
    attn_trans_kernel<<<dim3(64, 4, 128), dim3(32, 8), 0, stream>>>(attn, attnT);

    // --- out_pep_pre = attn^T @ v_pep -> bf16 (b, m, h*96+d) ---
    gemm_bf16<2><<<dim3(1, 16, 128), 256, 0, stream>>>(
        attnT, vpepT, opep, 2048, 96, 128, 128, 128, 768,
        2097152L, 262144L, 98304L, 12288L, 1572864L, 96L, nullptr, nullptr, 0);

    // --- tmp2 = out_pep_pre @ Wo_pep ---
    gemm_bf16<0><<<dim3(6, 256, 1), 256, 0, stream>>>(
        opep, WT5, tmp2, 32768, 768, 768, 768, 768, 768,
        0, 0, 0, 0, 0, 0, nullptr, nullptr, 0);
    bias_res_ln<<<32768, 256, 0, stream>>>(tmp2, bo_pep, protein, ln_g, ln_b, outQ);
}

// Round 3
// 831.518 us; speedup vs baseline: 3.0598x; 1.0988x over previous
//
#include <hip/hip_runtime.h>
#include <math.h>

static constexpr int HEADS  = 8;
static constexpr int DHEAD  = 96;
static constexpr int INNER  = 768;
static constexpr int NPEP   = 128;
static constexpr int MPRO   = 2048;
static constexpr float ATT_SCALE = 0.10206207261596577f;  // 96^-0.5
static constexpr float NEGF   = -1000000.0f;
static constexpr float LN_EPS = 1e-5f;

typedef __attribute__((ext_vector_type(8))) short bf16x8;
typedef __attribute__((ext_vector_type(4))) float f32x4;

__device__ __forceinline__ unsigned short f2b(float f) {
    unsigned u = __builtin_bit_cast(unsigned, f);
    u += 0x7fffu + ((u >> 16) & 1u);          // RNE
    return (unsigned short)(u >> 16);
}
__device__ __forceinline__ float b2f(unsigned short u) {
    return __builtin_bit_cast(float, (unsigned)u << 16);
}

__device__ __forceinline__ void async16(const unsigned short* g, unsigned short* l) {
    __builtin_amdgcn_global_load_lds(
        (const __attribute__((address_space(1))) void*)g,
        (__attribute__((address_space(3))) void*)l, 16, 0, 0);
}

// ---------------------------------------------------------------------------
// bf16 MFMA GEMM, B^T operand form: C[row,col] = sum_k A[row,k]*B[col,k]
// A: M x K row-major bf16 (lda). B: N x K row-major bf16 (ldb).
// TM x 128 tile, BK=32, 256 threads = 4 waves.
//   TM=128: waves 2x2 of 64x64.  TM=64: waves 2x2 of 32x64.
// Batched over blockIdx.z = b*HEADS+h via strides.
// MODE 1: scores -> bf16: v*SCALE, masked by mRow/mCol.
// MODE 2: bf16 row-major out (col<N guard), batched.
// MODE 3: bf16 head-split   (b,h,len,96) via lenShift.
// MODE 4: bf16 head-split-T (b,h,96,len).
// ---------------------------------------------------------------------------
template<int TM, int MODE>
__global__ __launch_bounds__(256) void gemm_bf16(
    const unsigned short* __restrict__ A, const unsigned short* __restrict__ B,
    unsigned short* __restrict__ C,
    int M, int N, int K, int lda, int ldb, int ldc,
    long sAb, long sAh, long sBb, long sBh, long sCb, long sCh,
    const int* __restrict__ mRow, const int* __restrict__ mCol, int lenShift)
{
    constexpr int FR = TM / 32;                 // row-fragments per wave
    __shared__ unsigned short As[TM * 32];
    __shared__ unsigned short Bs[128 * 32];

    const int tid = threadIdx.x;
    const int n0  = blockIdx.x * 128;
    const int m0  = blockIdx.y * TM;
    const int z   = blockIdx.z;
    const int zb  = z >> 3, zh = z & 7;

    const unsigned short* Ab = A + zb * sAb + zh * sAh;
    const unsigned short* Bb = B + zb * sBb + zh * sBh;

    const int rS = tid >> 2;
    const int kS = (tid & 3) * 8;
    const int wave = tid >> 6;
    unsigned short* ldsA0 = As + wave * 512;
    unsigned short* ldsA1 = As + 2048 + wave * 512;   // used only when TM==128
    unsigned short* ldsB0 = Bs + wave * 512;
    unsigned short* ldsB1 = Bs + 2048 + wave * 512;

    const int lane = tid & 63;
    const int l16  = lane & 15;
    const int quad = lane >> 4;
    const int wr   = (wave >> 1) * (TM / 2);
    const int wc   = (wave & 1) * 64;

    f32x4 acc[FR][4];
#pragma unroll
    for (int i = 0; i < FR; ++i)
#pragma unroll
        for (int j = 0; j < 4; ++j) acc[i][j] = (f32x4){0.f, 0.f, 0.f, 0.f};

    for (int k0 = 0; k0 < K; k0 += 32) {
        async16(Ab + (long)(m0 + rS) * lda + k0 + kS, ldsA0);
        if (TM == 128)
            async16(Ab + (long)(m0 + 64 + rS) * lda + k0 + kS, ldsA1);
        int bR0 = n0 + rS;      if (bR0 > N - 1) bR0 = N - 1;
        int bR1 = n0 + 64 + rS; if (bR1 > N - 1) bR1 = N - 1;
        async16(Bb + (long)bR0 * ldb + k0 + kS, ldsB0);
        async16(Bb + (long)bR1 * ldb + k0 + kS, ldsB1);
        __syncthreads();

        bf16x8 af[FR], bfr[4];
#pragma unroll
        for (int i = 0; i < FR; ++i)
            af[i] = *reinterpret_cast<const bf16x8*>(&As[(wr + i * 16 + l16) * 32 + quad * 8]);
#pragma unroll
        for (int j = 0; j < 4; ++j)
            bfr[j] = *reinterpret_cast<const bf16x8*>(&Bs[(wc + j * 16 + l16) * 32 + quad * 8]);
#pragma unroll
        for (int i = 0; i < FR; ++i)
#pragma unroll
            for (int j = 0; j < 4; ++j)
                acc[i][j] = __builtin_amdgcn_mfma_f32_16x16x32_bf16(af[i], bfr[j], acc[i][j], 0, 0, 0);
        __syncthreads();
    }

#pragma unroll
    for (int i = 0; i < FR; ++i) {
#pragma unroll
        for (int j = 0; j < 4; ++j) {
            const int col = n0 + wc + j * 16 + l16;
            if ((MODE == 2) && col >= N) continue;
            const int h = col / 96, d = col - h * 96;   // used by MODE 3/4
#pragma unroll
            for (int r = 0; r < 4; ++r) {
                const int row = m0 + wr + i * 16 + quad * 4 + r;
                float v = acc[i][j][r];
                if (MODE == 1) {
                    v *= ATT_SCALE;
                    if (mRow[zb * NPEP + row] == 0 || mCol[zb * MPRO + col] == 0) v = NEGF;
                    C[zb * sCb + zh * sCh + (long)row * ldc + col] = f2b(v);
                } else if (MODE == 2) {
                    C[zb * sCb + zh * sCh + (long)row * ldc + col] = f2b(v);
                } else if (MODE == 3) {
                    const int b = row >> lenShift, rr = row & ((1 << lenShift) - 1);
                    C[(((long)(b * 8 + h) << lenShift) + rr) * 96 + d] = f2b(v);
                } else { // MODE 4
                    const int b = row >> lenShift, rr = row & ((1 << lenShift) - 1);
                    C[(((long)(b * 8 + h) * 96 + d) << lenShift) + rr] = f2b(v);
                }
            }
        }
    }
}

// ---------------------------------------------------------------------------
// PV2: opep[b, m, h*96+d] = sum_n attn16[b,h,n,m] * vpepT[b,h,d,n]
// One block per (m-tile of 128, z=b*8+h). K = 128 (n), staged once:
// attn tile transposed through LDS, vpepT staged directly.
// ---------------------------------------------------------------------------
__global__ __launch_bounds__(256) void pv2_kernel(
    const unsigned short* __restrict__ attn16,
    const unsigned short* __restrict__ vpepT,
    unsigned short* __restrict__ opep)
{
    __shared__ unsigned short At[128 * 136];   // At[mLoc][n], padded row 136
    __shared__ unsigned short Bv[128 * 136];   // Bv[d][n]

    const int tid = threadIdx.x;
    const int m0  = blockIdx.x * 128;
    const int z   = blockIdx.y;
    const int b   = z >> 3, h = z & 7;

    const unsigned short* Az = attn16 + (long)z * NPEP * MPRO;   // [n][m] ld 2048
    const unsigned short* Bz = vpepT + (long)z * 96 * 128;       // [d][n] ld 128

    // stage Bv: 128 rows (clamp >=96), 128 cols
    {
        const int r = tid >> 1, half = tid & 1;
        const int rc = r > 95 ? 95 : r;
#pragma unroll
        for (int e = 0; e < 8; ++e) {
            bf16x8 v = *reinterpret_cast<const bf16x8*>(Bz + rc * 128 + half * 64 + e * 8);
            *reinterpret_cast<bf16x8*>(&Bv[r * 136 + half * 64 + e * 8]) = v;
        }
    }
    // stage At transposed: At[m][n] = Az[n][m0+m]
    {
        const int mBase = (tid & 7) * 16;
#pragma unroll
        for (int nn = 0; nn < 128; nn += 32) {
            const int n = nn + (tid >> 3);
#pragma unroll
            for (int c = 0; c < 2; ++c) {
                bf16x8 v = *reinterpret_cast<const bf16x8*>(Az + (long)n * MPRO + m0 + mBase + c * 8);
#pragma unroll
                for (int j = 0; j < 8; ++j)
                    At[(mBase + c * 8 + j) * 136 + n] = (unsigned short)v[j];
            }
        }
    }
    __syncthreads();

    const int lane = tid & 63;
    const int l16  = lane & 15;
    const int quad = lane >> 4;
    const int wave = tid >> 6;
    const int wr   = (wave >> 1) * 64;
    const int wc   = (wave & 1) * 64;

    f32x4 acc[4][4];
#pragma unroll
    for (int i = 0; i < 4; ++i)
#pragma unroll
        for (int j = 0; j < 4; ++j) acc[i][j] = (f32x4){0.f, 0.f, 0.f, 0.f};

#pragma unroll
    for (int kc = 0; kc < 4; ++kc) {
        bf16x8 af[4], bfr[4];
#pragma unroll
        for (int i = 0; i < 4; ++i)
            af[i] = *reinterpret_cast<const bf16x8*>(&At[(wr + i * 16 + l16) * 136 + kc * 32 + quad * 8]);
#pragma unroll
        for (int j = 0; j < 4; ++j)
            bfr[j] = *reinterpret_cast<const bf16x8*>(&Bv[(wc + j * 16 + l16) * 136 + kc * 32 + quad * 8]);
#pragma unroll
        for (int i = 0; i < 4; ++i)
#pragma unroll
            for (int j = 0; j < 4; ++j)
                acc[i][j] = __builtin_amdgcn_mfma_f32_16x16x32_bf16(af[i], bfr[j], acc[i][j], 0, 0, 0);
    }

#pragma unroll
    for (int i = 0; i < 4; ++i) {
#pragma unroll
        for (int j = 0; j < 4; ++j) {
            const int d = wc + j * 16 + l16;
            if (d >= 96) continue;
#pragma unroll
            for (int r = 0; r < 4; ++r) {
                const int m = m0 + wr + i * 16 + quad * 4 + r;
                opep[(long)b * MPRO * INNER + (long)m * INNER + h * 96 + d] = f2b(acc[i][j][r]);
            }
        }
    }
}

// ---------------------------------------------------------------------------
// fused fp32 -> bf16 conversion for protein then peptide
__global__ __launch_bounds__(256) void conv2_kernel(
    const float* __restrict__ pro, const float* __restrict__ pep,
    unsigned short* __restrict__ pro16, unsigned short* __restrict__ pep16,
    int nPro4, int nPep4)
{
    const int i = blockIdx.x * 256 + threadIdx.x;
    const float* in; unsigned short* out; int idx;
    if (i < nPro4) { in = pro; out = pro16; idx = i; }
    else { idx = i - nPro4; if (idx >= nPep4) return; in = pep; out = pep16; }
    float4 v = reinterpret_cast<const float4*>(in)[idx];
    ushort4 o;
    o.x = f2b(v.x); o.y = f2b(v.y); o.z = f2b(v.z); o.w = f2b(v.w);
    reinterpret_cast<ushort4*>(out)[idx] = o;
}

// weights: fp32 K x N (768x768) -> bf16 N x K (transposed), 6 via z
__global__ __launch_bounds__(256) void wtrans_kernel(
    const float* w0, const float* w1, const float* w2,
    const float* w3, const float* w4, const float* w5,
    unsigned short* o0, unsigned short* o1, unsigned short* o2,
    unsigned short* o3, unsigned short* o4, unsigned short* o5)
{
    const float* in; unsigned short* out;
    switch (blockIdx.z) {
        case 0: in = w0; out = o0; break;
        case 1: in = w1; out = o1; break;
        case 2: in = w2; out = o2; break;
        case 3: in = w3; out = o3; break;
        case 4: in = w4; out = o4; break;
        default: in = w5; out = o5; break;
    }
    __shared__ unsigned short t[32][33];
    const int bx = blockIdx.x * 32, by = blockIdx.y * 32;
    const int x = threadIdx.x, y = threadIdx.y;
#pragma unroll
    for (int i = 0; i < 32; i += 8)
        t[y + i][x] = f2b(in[(long)(by + y + i) * 768 + bx + x]);
    __syncthreads();
#pragma unroll
    for (int i = 0; i < 32; i += 8)
        out[(long)(bx + y + i) * 768 + by + x] = t[x][y + i];
}

// row softmax over 2048 bf16 scores: in-place bf16 normalize + fp32 attn out
__global__ __launch_bounds__(256) void softmax_kernel(
    unsigned short* __restrict__ s16, float* __restrict__ attn)
{
    __shared__ float smx[4], sms[4];
    const long row = blockIdx.x;
    unsigned short* p16 = s16 + row * (long)MPRO;
    float* pf = attn + row * (long)MPRO;
    const int tid = threadIdx.x;
    const int wv = tid >> 6;

    float v[8];
    float mx = -3.4e38f;
#pragma unroll
    for (int k = 0; k < 8; ++k) { v[k] = b2f(p16[tid + k * 256]); mx = fmaxf(mx, v[k]); }
#pragma unroll
    for (int off = 32; off > 0; off >>= 1) mx = fmaxf(mx, __shfl_xor(mx, off));
    if ((tid & 63) == 0) smx[wv] = mx;
    __syncthreads();
    mx = fmaxf(fmaxf(smx[0], smx[1]), fmaxf(smx[2], smx[3]));

    float sum = 0.f;
#pragma unroll
    for (int k = 0; k < 8; ++k) { v[k] = __expf(v[k] - mx); sum += v[k]; }
#pragma unroll
    for (int off = 32; off > 0; off >>= 1) sum += __shfl_xor(sum, off);
    if ((tid & 63) == 0) sms[wv] = sum;
    __syncthreads();
    const float inv = 1.0f / (sms[0] + sms[1] + sms[2] + sms[3]);
#pragma unroll
    for (int k = 0; k < 8; ++k) {
        const float o = v[k] * inv;
        pf[tid + k * 256] = o;
        p16[tid + k * 256] = f2b(o);
    }
}

// out = LN(b2f(tmp) + bias + res) * g + b, rows of 768
__global__ __launch_bounds__(256) void bias_res_ln(
    const unsigned short* __restrict__ tmp, const float* __restrict__ bias,
    const float* __restrict__ res, const float* __restrict__ gam,
    const float* __restrict__ bet, float* __restrict__ out)
{
    __shared__ float red[8];
    const long row = blockIdx.x;
    const unsigned short* t = tmp + row * INNER;
    const float* r = res + row * INNER;
    float* o = out + row * INNER;
    const int tid = threadIdx.x;
    const int wv = tid >> 6;

    float v[3]; float s = 0.f;
#pragma unroll
    for (int k = 0; k < 3; ++k) { const int c = tid + k * 256; v[k] = b2f(t[c]) + bias[c] + r[c]; s += v[k]; }
#pragma unroll
    for (int off = 32; off > 0; off >>= 1) s += __shfl_xor(s, off);
    if ((tid & 63) == 0) red[wv] = s;
    __syncthreads();
    const float mu = (red[0] + red[1] + red[2] + red[3]) * (1.0f / INNER);

    float vs = 0.f;
#pragma unroll
    for (int k = 0; k < 3; ++k) { const float d = v[k] - mu; vs += d * d; }
#pragma unroll
    for (int off = 32; off > 0; off >>= 1) vs += __shfl_xor(vs, off);
    if ((tid & 63) == 0) red[4 + wv] = vs;
    __syncthreads();
    const float rstd = rsqrtf((red[4] + red[5] + red[6] + red[7]) * (1.0f / INNER) + LN_EPS);
#pragma unroll
    for (int k = 0; k < 3; ++k) { const int c = tid + k * 256; o[c] = (v[k] - mu) * rstd * gam[c] + bet[c]; }
}

// ---------------------------------------------------------------------------
extern "C" void kernel_launch(void* const* d_in, const int* in_sizes, int n_in,
                              void* d_out, int out_size, void* d_ws, size_t ws_size,
                              hipStream_t stream)
{
    (void)in_sizes; (void)n_in; (void)out_size; (void)ws_size;

    const float* peptide = (const float*)d_in[0];
    const float* protein = (const float*)d_in[1];
    const int*   pepm    = (const int*)  d_in[2];
    const int*   prom    = (const int*)  d_in[3];
    const float* Wq      = (const float*)d_in[4];
    const float* Wk      = (const float*)d_in[5];
    const float* Wv_prot = (const float*)d_in[6];
    const float* Wv_pep  = (const float*)d_in[7];
    const float* Wo_prot = (const float*)d_in[8];
    const float* bo_prot = (const float*)d_in[9];
    const float* Wo_pep  = (const float*)d_in[10];
    const float* bo_pep  = (const float*)d_in[11];
    const float* ln_g    = (const float*)d_in[12];
    const float* ln_b    = (const float*)d_in[13];

    // --- workspace layout (byte offsets, aliased; peak 181,141,504 B) ---
    char* ws = (char*)d_ws;
    auto U = [&](size_t off) { return (unsigned short*)(ws + off); };
    unsigned short* WT0   = U(0);             // 6 x 1179648, live throughout
    unsigned short* WT1   = U(1179648);
    unsigned short* WT2   = U(2 * 1179648);
    unsigned short* WT3   = U(3 * 1179648);
    unsigned short* WT4   = U(4 * 1179648);
    unsigned short* WT5   = U(5 * 1179648);
    unsigned short* q16   = U(7077888);       // 3145728   [projQ, scores]
    unsigned short* k16   = U(10223616);      // 50331648  [projK, scores]
    unsigned short* vpT   = U(60555264);      // 50331648  [projVprot, PV1]
    unsigned short* vpepT = U(110886912);     // 3145728   [projVpep, PV2]
    unsigned short* s16   = U(114032640);     // 67108864  [scores, PV2] (attn16 in place)
    unsigned short* pro16 = U(114032640);     // 50331648  [conv, projVprot] (pre-scores)
    unsigned short* pep16 = U(164364288);     // 3145728   [conv, projVpep]  (pre-scores)
    unsigned short* opp   = U(7077888);       // 3145728   [PV1, O1]  over dead q16
    unsigned short* tmp1  = U(10223616);      // 3145728   [O1, LN1]  over dead k16 head
    unsigned short* opep  = U(13369344);      // 50331648  [PV2, O2]  over dead k16/vpT head
    unsigned short* tmp2  = U(63700992);      // 50331648  [O2, LN2]  over dead vpT/vpepT

    float* outP = (float*)d_out;                  // (16,128,768)
    float* outQ = outP + 16 * 128 * 768;          // (16,2048,768)
    float* attn = outQ + (long)16 * 2048 * 768;   // (16,8,128,2048) fp32

    // 1. bf16 conversions (one launch) + weight transposes
    conv2_kernel<<<26112, 256, 0, stream>>>(protein, peptide, pro16, pep16, 6291456, 393216);
    wtrans_kernel<<<dim3(24, 24, 6), dim3(32, 8), 0, stream>>>(
        Wq, Wk, Wv_prot, Wv_pep, Wo_prot, Wo_pep, WT0, WT1, WT2, WT3, WT4, WT5);

    // 2. projections (head-split outputs)
    gemm_bf16<128, 3><<<dim3(6, 16, 1), 256, 0, stream>>>(
        pep16, WT0, q16, 2048, 768, 768, 768, 768, 0,
        0, 0, 0, 0, 0, 0, nullptr, nullptr, 7);
    gemm_bf16<128, 3><<<dim3(6, 256, 1), 256, 0, stream>>>(
        pro16, WT1, k16, 32768, 768, 768, 768, 768, 0,
        0, 0, 0, 0, 0, 0, nullptr, nullptr, 11);
    gemm_bf16<128, 4><<<dim3(6, 256, 1), 256, 0, stream>>>(
        pro16, WT2, vpT, 32768, 768, 768, 768, 768, 0,
        0, 0, 0, 0, 0, 0, nullptr, nullptr, 11);
    gemm_bf16<128, 4><<<dim3(6, 16, 1), 256, 0, stream>>>(
        pep16, WT3, vpepT, 2048, 768, 768, 768, 768, 0,
        0, 0, 0, 0, 0, 0, nullptr, nullptr, 7);

    // 3. scores = scale * q.k masked -> bf16
    gemm_bf16<128, 1><<<dim3(16, 1, 128), 256, 0, stream>>>(
        q16, k16, s16, 128, 2048, 96, 96, 96, 2048,
        98304L, 12288L, 1572864L, 196608L, 2097152L, 262144L, pepm, prom, 0);

    // 4. softmax: fp32 attn to d_out + bf16 in place
    softmax_kernel<<<16384, 256, 0, stream>>>(s16, attn);

    // 5. PV1: out_prot_pre = attn @ v_prot -> bf16 (b,n,h*96+d)
    gemm_bf16<64, 2><<<dim3(1, 2, 128), 256, 0, stream>>>(
        s16, vpT, opp, 128, 96, 2048, 2048, 2048, 768,
        2097152L, 262144L, 1572864L, 196608L, 98304L, 96L, nullptr, nullptr, 0);

    // 6. O1 + LN1
    gemm_bf16<64, 2><<<dim3(6, 32, 1), 256, 0, stream>>>(
        opp, WT4, tmp1, 2048, 768, 768, 768, 768, 768,
        0, 0, 0, 0, 0, 0, nullptr, nullptr, 0);
    bias_res_ln<<<2048, 256, 0, stream>>>(tmp1, bo_prot, peptide, ln_g, ln_b, outP);

    // 7. PV2 (in-LDS transpose of attn16)
    pv2_kernel<<<dim3(16, 128), 256, 0, stream>>>(s16, vpepT, opep);

    // 8. O2 + LN2
    gemm_bf16<128, 2><<<dim3(6, 256, 1), 256, 0, stream>>>(
        opep, WT5, tmp2, 32768, 768, 768, 768, 768, 768,
        0, 0, 0, 0, 0, 0, nullptr, nullptr, 0);
    bias_res_ln<<<32768, 256, 0, stream>>>(tmp2, bo_pep, protein, ln_g, ln_b, outQ);
}